// Round 17
// baseline (255.955 us; speedup 1.0000x reference)
//
#include <hip/hip_runtime.h>

#define R_ 8
#define N_ 4096
#define D_ 128
#define BM 64
#define KSPLIT 2

typedef __attribute__((ext_vector_type(8))) short bf16x8;
typedef __attribute__((ext_vector_type(4))) float f32x4;

__device__ __forceinline__ unsigned short f2bf(float f) {
  unsigned int u = __builtin_bit_cast(unsigned int, f);
  u += 0x7FFFu + ((u >> 16) & 1u);   // RNE
  return (unsigned short)(u >> 16);
}
__device__ __forceinline__ unsigned int pk2(float lo, float hi) {
  return (unsigned int)f2bf(lo) | ((unsigned int)f2bf(hi) << 16);
}
// quantize 4 floats in [0,1) to u8 (value*256, RN, clamp 255), packed LE
__device__ __forceinline__ unsigned int quant4(f32x4 a) {
  unsigned int q0 = (unsigned int)fminf(fmaf(a.x, 256.f, 0.5f), 255.5f);
  unsigned int q1 = (unsigned int)fminf(fmaf(a.y, 256.f, 0.5f), 255.5f);
  unsigned int q2 = (unsigned int)fminf(fmaf(a.z, 256.f, 0.5f), 255.5f);
  unsigned int q3 = (unsigned int)fminf(fmaf(a.w, 256.f, 0.5f), 255.5f);
  return q0 | (q1 << 8) | (q2 << 16) | (q3 << 24);
}

// async global->LDS, 16 B per lane; LDS dest is wave-uniform base + lane*16
__device__ __forceinline__ void gld16(const void* g, void* l) {
  using GP = const __attribute__((address_space(1))) unsigned int*;
  using LP = __attribute__((address_space(3))) unsigned int*;
  __builtin_amdgcn_global_load_lds((GP)g, (LP)l, 16, 0, 0);
}

// Merged init (R16 verbatim): embTt tiled for layer-1 B-direct; relb bf16.
__global__ void k_init(const float* __restrict__ emb, const float* __restrict__ rel,
                       unsigned short* __restrict__ embTt, unsigned short* __restrict__ relb) {
  int b = blockIdx.x;
  if (b < 256) {
    int gt = b * 256 + threadIdx.x;           // 64K threads, one 16B unit each
    int C = gt >> 6, l = gt & 63;
    int d = (C & 7) * 16 + (l & 15);
    int k = (C >> 3) * 32 + (l >> 4) * 8;
    unsigned short v[8];
#pragma unroll
    for (int i = 0; i < 8; ++i)
      v[i] = f2bf(emb[(size_t)(k + i) * D_ + d]);
    *(uint4*)(embTt + ((size_t)C * 64 + l) * 8) = *(const uint4*)v;
  } else {
    int i = (b - 256) * 256 + threadIdx.x;    // over R*D*D
    relb[i] = f2bf(rel[i]);
  }
}

// ---- Layer-1 GEMM: fp32 adj, BK=256 (1 KB per adj row visit), A-only LDS 64 KB
//      (2 blocks/CU), B direct-to-reg from tiled embTt, fused u8 quant-out.
// adj8 keying unchanged: G = z*64 + t*8 + kk; byte (G*2+wr)*1024 + lane*16. ----
__global__ __launch_bounds__(256, 2) void gcn_gemm1(
    const float* __restrict__ adj,            // [R][N][N] fp32
    const unsigned short* __restrict__ embTt, // tiled [128 G][8 dblk][1 KB] bf16
    unsigned char* __restrict__ adj8,         // [R*64 tiles][256 KB] u8 tiled
    unsigned short* __restrict__ agg_p)       // [KSPLIT][R][N][D] bf16
{
  __shared__ float As[BM * 256];              // 64 KB: row r chunk; slot s at s^(r&15)

  const int tid  = threadIdx.x;
  const int lane = tid & 63;
  const int w    = tid >> 6;
  const int wr = w >> 1, wc = w & 1;          // 2x2 waves: 32 rows x 64 cols each
  const int fr  = lane & 15;
  const int g   = lane >> 4;                  // 0..3
  const int cr4 = g * 4;

  const int ntile = blockIdx.x;
  const int r     = blockIdx.y;
  const int z     = blockIdx.z;
  const int row0  = ntile * BM;
  const int k0    = z * (N_ / KSPLIT);
  const size_t tbase = (size_t)(r * 64 + ntile) * 262144;   // 256 KB per tile

  const float* gAr = adj + ((size_t)r * N_ + row0) * N_ + k0;

  // B chunk loader: group G, d-block DB = wc*4+n -> 16 B at chunk(G,DB) + lane*16
  #define BLOAD(G, n) (*(const bf16x8*)(embTt + ((((size_t)(G) * 8) + wc * 4 + (n)) * 64 + lane) * 8))

  bf16x8 bcur[4], bnxt[4];
#pragma unroll
  for (int n = 0; n < 4; ++n) bcur[n] = BLOAD(z * 64, n);

  f32x4 acc[2][4];
#pragma unroll
  for (int m = 0; m < 2; ++m)
#pragma unroll
    for (int n = 0; n < 4; ++n)
      acc[m][n] = (f32x4){0.f, 0.f, 0.f, 0.f};

  for (int t = 0; t < 8; ++t) {               // NSTEP = 2048/256
    const int ko = t * 256;
    // A: 16 instrs/wave, ONE full 1 KB row-chunk each (64 lanes x 16 B);
    // source carries the swizzle: slot = lane ^ (row & 15)
#pragma unroll
    for (int i = 0; i < 16; ++i) {
      const int row = w * 16 + i;             // wave-uniform
      gld16(gAr + (size_t)row * N_ + ko + (size_t)((lane ^ (row & 15)) * 4),
            As + row * 256);
    }
    __syncthreads();                          // drain DMA -> A tile resident

#pragma unroll
    for (int kk = 0; kk < 8; ++kk) {
      // prefetch B for next kk (wrap at step/loop end; wrapped value unused)
      const int Gn = (kk < 7) ? (z * 64 + t * 8 + kk + 1)
                              : ((t + 1 < 8) ? z * 64 + (t + 1) * 8 : z * 64);
#pragma unroll
      for (int n = 0; n < 4; ++n) bnxt[n] = BLOAD(Gn, n);

      bf16x8 af[2];
      uint4 qv;
#pragma unroll
      for (int m = 0; m < 2; ++m) {
        const int row = wr * 32 + m * 16 + fr;
        const int s0  = kk * 8 + g * 2;       // 16-B slot of this lane's k8 (f32)
        f32x4 a0 = *(const f32x4*)&As[row * 256 + (((s0    ) ^ (row & 15)) * 4)];
        f32x4 a1 = *(const f32x4*)&As[row * 256 + (((s0 + 1) ^ (row & 15)) * 4)];
        unsigned int* ap = (unsigned int*)&af[m];
        ap[0] = pk2(a0.x, a0.y); ap[1] = pk2(a0.z, a0.w);
        ap[2] = pk2(a1.x, a1.y); ap[3] = pk2(a1.z, a1.w);
        if (wc == 0) {
          if (m == 0) { qv.x = quant4(a0); qv.y = quant4(a1); }
          else        { qv.z = quant4(a0); qv.w = quant4(a1); }
        }
      }
      if (wc == 0) {
        const int G = z * 64 + t * 8 + kk;    // absolute 32-col K-group
        *(uint4*)(adj8 + tbase + (size_t)(G * 2 + wr) * 1024 + (size_t)lane * 16) = qv;
      }
#pragma unroll
      for (int m = 0; m < 2; ++m)
#pragma unroll
        for (int n = 0; n < 4; ++n)
          acc[m][n] = __builtin_amdgcn_mfma_f32_16x16x32_bf16(af[m], bcur[n], acc[m][n], 0, 0, 0);
#pragma unroll
      for (int n = 0; n < 4; ++n) bcur[n] = bnxt[n];
    }
    __syncthreads();                          // protect LDS overwrite next step
  }
  #undef BLOAD

  unsigned short* gO = agg_p + (((size_t)z * R_ + r) * N_ + row0) * D_;
#pragma unroll
  for (int m = 0; m < 2; ++m)
#pragma unroll
    for (int n = 0; n < 4; ++n)
#pragma unroll
      for (int j = 0; j < 4; ++j) {
        int rl = wr * 32 + m * 16 + cr4 + j;
        int cl = wc * 64 + n * 16 + fr;
        gO[(size_t)rl * D_ + cl] = f2bf(acc[m][n][j]);
      }
}

// ---- Layer-2 GEMM (R15 verbatim): u8 tiled adj, BK=128, mf1/nf8 waves ----
__global__ __launch_bounds__(256, 4) void gcn_gemm2(
    const unsigned char* __restrict__ adj8,   // tiled u8 (from gemm1)
    const unsigned short* __restrict__ embT,  // [D][N] bf16, scaled 1/256
    unsigned short* __restrict__ agg_p)       // [KSPLIT][R][N][D] bf16
{
  __shared__ unsigned char  A8[2 * 4096];     // 8 KB: two 4 KB S-tiles, linear
  __shared__ unsigned short Bs[D_ * 128];     // 32 KB: slot s stored at s^(d&15)

  const int tid  = threadIdx.x;
  const int lane = tid & 63;
  const int w    = tid >> 6;                  // wave w: rows w*16 .. w*16+16
  const int fr   = lane & 15;
  const int g    = lane >> 4;
  const int cr4  = g * 4;

  const int ntile = blockIdx.x;
  const int r     = blockIdx.y;
  const int z     = blockIdx.z;
  const int row0  = ntile * BM;
  const int k0    = z * (N_ / KSPLIT);
  const size_t tbase = (size_t)(r * 64 + ntile) * 262144;

  f32x4 acc[8];
#pragma unroll
  for (int n = 0; n < 8; ++n)
    acc[n] = (f32x4){0.f, 0.f, 0.f, 0.f};

  for (int t = 0; t < 16; ++t) {              // BK=128 steps
    const int S0 = z * 32 + t * 2;            // two consecutive 64-K S-tiles
#pragma unroll
    for (int i = 0; i < 2; ++i) {
      const int c = i * 4 + w;
      gld16(adj8 + tbase + (size_t)S0 * 4096 + (size_t)c * 1024 + (size_t)lane * 16,
            A8 + c * 1024);
    }
#pragma unroll
    for (int i = 0; i < 8; ++i) {
      const int rowbase = (w * 8 + i) * 4;
      const int d    = rowbase + (lane >> 4);
      const int slot = (lane & 15) ^ (d & 15);
      gld16(embT + (size_t)d * N_ + k0 + t * 128 + slot * 8, Bs + rowbase * 128);
    }
    __syncthreads();

#pragma unroll
    for (int kk = 0; kk < 4; ++kk) {
      unsigned long long v = *(const unsigned long long*)
          &A8[(kk >> 1) * 4096 + (((kk & 1) * 2 + (w >> 1)) * 64 + lane) * 16 + (w & 1) * 8];
      bf16x8 af;
      unsigned int* ap = (unsigned int*)&af;
      ap[0] = pk2((float)((unsigned)(v      ) & 255), (float)((unsigned)(v >>  8) & 255));
      ap[1] = pk2((float)((unsigned)(v >> 16) & 255), (float)((unsigned)(v >> 24) & 255));
      ap[2] = pk2((float)((unsigned)(v >> 32) & 255), (float)((unsigned)(v >> 40) & 255));
      ap[3] = pk2((float)((unsigned)(v >> 48) & 255), (float)((unsigned)(v >> 56) & 255));
#pragma unroll
      for (int n = 0; n < 8; ++n) {
        const int d = n * 16 + fr;
        bf16x8 bfr = *(const bf16x8*)&Bs[d * 128 + (((kk * 4 + g) ^ (d & 15)) * 8)];
        acc[n] = __builtin_amdgcn_mfma_f32_16x16x32_bf16(af, bfr, acc[n], 0, 0, 0);
      }
    }
    __syncthreads();
  }

  unsigned short* gO = agg_p + (((size_t)z * R_ + r) * N_ + row0) * D_;
#pragma unroll
  for (int n = 0; n < 8; ++n)
#pragma unroll
    for (int j = 0; j < 4; ++j) {
      int rl = w * 16 + cr4 + j;
      int cl = n * 16 + fr;
      gO[(size_t)rl * D_ + cl] = f2bf(acc[n][j]);
    }
}

// Pass 2 (R15 verbatim): tmp = agg_p @ rel^T summed over z,r; out = relu(mean_r);
// embT ([d][n], scaled 1/256) for gemm2's B staging.
__global__ __launch_bounds__(256) void gcn_pass2(
    const unsigned short* __restrict__ agg_p,  // [KSPLIT][R][N][D] bf16
    const unsigned short* __restrict__ relb,   // [R][D][D] bf16
    float* __restrict__ out,                   // [N][D] f32
    unsigned short* __restrict__ embT,         // [D][N] bf16
    int write_out, int write_embT)
{
  const int tid  = threadIdx.x;
  const int lane = tid & 63;
  const int w    = tid >> 6;
  const int n0   = blockIdx.x * 16;
  const int col0 = w * 32;
  const int fr   = lane & 15;
  const int e8   = (lane >> 4) * 8;
  const int cr4  = (lane >> 4) * 4;

  f32x4 tacc[2];
  tacc[0] = (f32x4){0.f, 0.f, 0.f, 0.f};
  tacc[1] = (f32x4){0.f, 0.f, 0.f, 0.f};

  for (int r = 0; r < R_; ++r) {
    bf16x8 a[2][4], b[2][4];
#pragma unroll
    for (int zz = 0; zz < 2; ++zz)
#pragma unroll
      for (int kk = 0; kk < 4; ++kk)
        a[zz][kk] = *(const bf16x8*)&agg_p[(((size_t)zz * R_ + r) * N_ + n0 + fr) * D_ + kk * 32 + e8];
#pragma unroll
    for (int n = 0; n < 2; ++n)
#pragma unroll
      for (int kk = 0; kk < 4; ++kk)
        b[n][kk] = *(const bf16x8*)&relb[(size_t)r * D_ * D_ + (col0 + n * 16 + fr) * D_ + kk * 32 + e8];
#pragma unroll
    for (int n = 0; n < 2; ++n)
#pragma unroll
      for (int kk = 0; kk < 4; ++kk)
#pragma unroll
        for (int zz = 0; zz < 2; ++zz)
          tacc[n] = __builtin_amdgcn_mfma_f32_16x16x32_bf16(a[zz][kk], b[n][kk], tacc[n], 0, 0, 0);
  }

#pragma unroll
  for (int n = 0; n < 2; ++n)
#pragma unroll
    for (int j = 0; j < 4; ++j) {
      int row = n0 + cr4 + j;
      int col = col0 + n * 16 + fr;
      float v = tacc[n][j] * 0.125f;
      v = v > 0.f ? v : 0.f;
      if (write_out)  out[(size_t)row * D_ + col] = v;
      if (write_embT) embT[(size_t)col * N_ + row] = f2bf(v * 0.00390625f);  // fold 1/256 for u8 layer-2
    }
}

extern "C" void kernel_launch(void* const* d_in, const int* in_sizes, int n_in,
                              void* d_out, int out_size, void* d_ws, size_t ws_size,
                              hipStream_t stream) {
  const float* adj = (const float*)d_in[0];   // [R][N][N]
  const float* emb = (const float*)d_in[1];   // [N][D]
  const float* rel = (const float*)d_in[2];   // [R][D][D]
  float* out = (float*)d_out;                 // [N][D] f32

  unsigned short* embTt = (unsigned short*)d_ws;                 // 1 MB  (tiled, layer-1)
  unsigned short* embT  = embTt + (size_t)N_ * D_;               // 1 MB  ([d][n], layer-2)
  unsigned short* relb  = embT + (size_t)N_ * D_;                // 256 KB
  unsigned short* agg_p = relb + (size_t)R_ * D_ * D_;           // 16 MB
  unsigned char*  adj8  = (unsigned char*)(agg_p + (size_t)2 * R_ * N_ * D_);  // 128 MB

  k_init<<<256 + 512, 256, 0, stream>>>(emb, rel, embTt, relb);

  dim3 grid(N_ / BM, R_, KSPLIT);
  gcn_gemm1<<<grid, 256, 0, stream>>>(adj, embTt, adj8, agg_p);
  gcn_pass2<<<N_ / 16, 256, 0, stream>>>(agg_p, relb, out, embT, /*write_out=*/0, /*write_embT=*/1);
  gcn_gemm2<<<grid, 256, 0, stream>>>(adj8, embT, agg_p);
  gcn_pass2<<<N_ / 16, 256, 0, stream>>>(agg_p, relb, out, embT, /*write_out=*/1, /*write_embT=*/0);
}

// Round 18
// 255.292 us; speedup vs baseline: 1.0026x; 1.0026x over previous
//
#include <hip/hip_runtime.h>

#define R_ 8
#define N_ 4096
#define D_ 128
#define BM 64
#define KSPLIT 2

typedef __attribute__((ext_vector_type(8))) short bf16x8;
typedef __attribute__((ext_vector_type(4))) float f32x4;

__device__ __forceinline__ unsigned short f2bf(float f) {
  unsigned int u = __builtin_bit_cast(unsigned int, f);
  u += 0x7FFFu + ((u >> 16) & 1u);   // RNE
  return (unsigned short)(u >> 16);
}
__device__ __forceinline__ unsigned int pk2(float lo, float hi) {
  return (unsigned int)f2bf(lo) | ((unsigned int)f2bf(hi) << 16);
}
// quantize 4 floats in [0,1) to u8 (value*256, RN, clamp 255), packed LE
__device__ __forceinline__ unsigned int quant4(f32x4 a) {
  unsigned int q0 = (unsigned int)fminf(fmaf(a.x, 256.f, 0.5f), 255.5f);
  unsigned int q1 = (unsigned int)fminf(fmaf(a.y, 256.f, 0.5f), 255.5f);
  unsigned int q2 = (unsigned int)fminf(fmaf(a.z, 256.f, 0.5f), 255.5f);
  unsigned int q3 = (unsigned int)fminf(fmaf(a.w, 256.f, 0.5f), 255.5f);
  return q0 | (q1 << 8) | (q2 << 16) | (q3 << 24);
}

// async global->LDS, 16 B per lane; LDS dest is wave-uniform base + lane*16
__device__ __forceinline__ void gld16(const void* g, void* l) {
  using GP = const __attribute__((address_space(1))) unsigned int*;
  using LP = __attribute__((address_space(3))) unsigned int*;
  __builtin_amdgcn_global_load_lds((GP)g, (LP)l, 16, 0, 0);
}

// merged init: embN bf16 [n][d]; relb bf16; zero outacc1/outacc2
__global__ void k_init(const float* __restrict__ emb, const float* __restrict__ rel,
                       unsigned short* __restrict__ embN, unsigned short* __restrict__ relb,
                       float* __restrict__ outacc1, float* __restrict__ outacc2) {
  int b = blockIdx.x;
  if (b < 2048) {
    int i = b * 256 + threadIdx.x;            // N*D elementwise
    embN[i] = f2bf(emb[i]);
  } else if (b < 2560) {
    int i = (b - 2048) * 256 + threadIdx.x;   // R*D*D
    relb[i] = f2bf(rel[i]);
  } else if (b < 4608) {
    int i = (b - 2560) * 256 + threadIdx.x;   // N*D
    outacc1[i] = 0.f;
  } else {
    int i = (b - 4608) * 256 + threadIdx.x;   // N*D
    outacc2[i] = 0.f;
  }
}

// ET1[r][e][n] = sum_d rel[r][e][d] * emb[n][d]   (bf16); grid (64 ntile, 8 r)
__global__ __launch_bounds__(256) void k_makeET1(
    const unsigned short* __restrict__ relb,   // [R][D][D] bf16
    const unsigned short* __restrict__ embN,   // [N][D] bf16
    unsigned short* __restrict__ ET1)          // [R][D][N] bf16
{
  const int lane = threadIdx.x & 63;
  const int w    = threadIdx.x >> 6;           // wave w: e-rows w*32..+32
  const int fr   = lane & 15;
  const int g    = lane >> 4;
  const int cr4  = g * 4;
  const int n0   = blockIdx.x * 64;
  const int r    = blockIdx.y;
  const unsigned short* rb = relb + (size_t)r * D_ * D_;

  f32x4 acc[2][4];
#pragma unroll
  for (int m = 0; m < 2; ++m)
#pragma unroll
    for (int n = 0; n < 4; ++n) acc[m][n] = (f32x4){0.f, 0.f, 0.f, 0.f};

#pragma unroll
  for (int ks = 0; ks < 4; ++ks) {
    bf16x8 a[2], b[4];
#pragma unroll
    for (int m = 0; m < 2; ++m)
      a[m] = *(const bf16x8*)&rb[(w * 32 + m * 16 + fr) * D_ + ks * 32 + g * 8];
#pragma unroll
    for (int n = 0; n < 4; ++n)
      b[n] = *(const bf16x8*)&embN[(size_t)(n0 + n * 16 + fr) * D_ + ks * 32 + g * 8];
#pragma unroll
    for (int m = 0; m < 2; ++m)
#pragma unroll
      for (int n = 0; n < 4; ++n)
        acc[m][n] = __builtin_amdgcn_mfma_f32_16x16x32_bf16(a[m], b[n], acc[m][n], 0, 0, 0);
  }
  unsigned short* o = ET1 + (size_t)r * D_ * N_;
#pragma unroll
  for (int m = 0; m < 2; ++m)
#pragma unroll
    for (int n = 0; n < 4; ++n)
#pragma unroll
      for (int j = 0; j < 4; ++j)
        o[(size_t)(w * 32 + m * 16 + cr4 + j) * N_ + n0 + n * 16 + fr] = f2bf(acc[m][n][j]);
}

// ET2[r][e][n] = sum_d rel[r][e][d] * relu(outacc1[n][d])/256   (bf16)
__global__ __launch_bounds__(256) void k_makeET2(
    const unsigned short* __restrict__ relb,   // [R][D][D] bf16
    const float* __restrict__ outacc1,         // [N][D] f32 (pre-relu layer-1 out)
    unsigned short* __restrict__ ET2)          // [R][D][N] bf16
{
  const int lane = threadIdx.x & 63;
  const int w    = threadIdx.x >> 6;
  const int fr   = lane & 15;
  const int g    = lane >> 4;
  const int cr4  = g * 4;
  const int n0   = blockIdx.x * 64;
  const int r    = blockIdx.y;
  const unsigned short* rb = relb + (size_t)r * D_ * D_;

  f32x4 acc[2][4];
#pragma unroll
  for (int m = 0; m < 2; ++m)
#pragma unroll
    for (int n = 0; n < 4; ++n) acc[m][n] = (f32x4){0.f, 0.f, 0.f, 0.f};

#pragma unroll
  for (int ks = 0; ks < 4; ++ks) {
    bf16x8 a[2], b[4];
#pragma unroll
    for (int m = 0; m < 2; ++m)
      a[m] = *(const bf16x8*)&rb[(w * 32 + m * 16 + fr) * D_ + ks * 32 + g * 8];
#pragma unroll
    for (int n = 0; n < 4; ++n) {
      const float* p = &outacc1[(size_t)(n0 + n * 16 + fr) * D_ + ks * 32 + g * 8];
      f32x4 v0 = *(const f32x4*)p, v1 = *(const f32x4*)(p + 4);
      unsigned int* bp = (unsigned int*)&b[n];
      const float s = 0.00390625f;
      bp[0] = pk2(fmaxf(v0.x, 0.f) * s, fmaxf(v0.y, 0.f) * s);
      bp[1] = pk2(fmaxf(v0.z, 0.f) * s, fmaxf(v0.w, 0.f) * s);
      bp[2] = pk2(fmaxf(v1.x, 0.f) * s, fmaxf(v1.y, 0.f) * s);
      bp[3] = pk2(fmaxf(v1.z, 0.f) * s, fmaxf(v1.w, 0.f) * s);
    }
#pragma unroll
    for (int m = 0; m < 2; ++m)
#pragma unroll
      for (int n = 0; n < 4; ++n)
        acc[m][n] = __builtin_amdgcn_mfma_f32_16x16x32_bf16(a[m], b[n], acc[m][n], 0, 0, 0);
  }
  unsigned short* o = ET2 + (size_t)r * D_ * N_;
#pragma unroll
  for (int m = 0; m < 2; ++m)
#pragma unroll
    for (int n = 0; n < 4; ++n)
#pragma unroll
      for (int j = 0; j < 4; ++j)
        o[(size_t)(w * 32 + m * 16 + cr4 + j) * N_ + n0 + n * 16 + fr] = f2bf(acc[m][n][j]);
}

// ---- Layer-1 GEMM (R14 main loop): fp32 adj, BK=128, B from ET1[r]; fused u8
//      quant-out; epilogue atomicAdds tmp-partial*0.125 into outacc1. ----
__global__ __launch_bounds__(256, 2) void gcn_gemm1(
    const float* __restrict__ adj,            // [R][N][N] fp32
    const unsigned short* __restrict__ ET1,   // [R][D][N] bf16
    unsigned char* __restrict__ adj8,         // [R*64 tiles][256 KB] u8 tiled
    float* __restrict__ outacc1)              // [N][D] f32 atomic accumulator
{
  __shared__ float          As[BM * 128];     // 32 KB: slot s stored at s^(row&15)
  __shared__ unsigned short Bs[D_ * 128];     // 32 KB: slot s stored at s^(e&15)

  const int tid  = threadIdx.x;
  const int lane = tid & 63;
  const int w    = tid >> 6;
  const int wr = w >> 1, wc = w & 1;          // 2x2 waves: 32 rows x 64 cols each
  const int fr  = lane & 15;
  const int g   = lane >> 4;                  // 0..3
  const int cr4 = g * 4;

  const int ntile = blockIdx.x;
  const int r     = blockIdx.y;
  const int z     = blockIdx.z;
  const int row0  = ntile * BM;
  const int k0    = z * (N_ / KSPLIT);
  const size_t tbase = (size_t)(r * 64 + ntile) * 262144;   // 256 KB per tile

  const float* gAr = adj + ((size_t)r * N_ + row0) * N_ + k0;
  const unsigned short* Er = ET1 + (size_t)r * D_ * N_;

  f32x4 acc[2][4];
#pragma unroll
  for (int m = 0; m < 2; ++m)
#pragma unroll
    for (int n = 0; n < 4; ++n)
      acc[m][n] = (f32x4){0.f, 0.f, 0.f, 0.f};

  for (int t = 0; t < 16; ++t) {              // NSTEP = 2048/128
    const int ko = t * 128;
    // A: 8 instrs/wave, each 1 KB = 2 rows x 512 B (32 slots); source pre-swizzled
#pragma unroll
    for (int i = 0; i < 8; ++i) {
      const int rowbase = w * 16 + i * 2;
      const int ra   = rowbase + (lane >> 5);
      const int slot = (lane & 31) ^ (ra & 15);
      gld16(gAr + (size_t)ra * N_ + ko + slot * 4, As + rowbase * 128);
    }
    // B: 8 instrs/wave, each 1 KB = 4 e-rows x 256 B (16 slots); source pre-swizzled
#pragma unroll
    for (int i = 0; i < 8; ++i) {
      const int rowbase = (w * 8 + i) * 4;
      const int e    = rowbase + (lane >> 4);
      const int slot = (lane & 15) ^ (e & 15);
      gld16(Er + (size_t)e * N_ + k0 + ko + slot * 8, Bs + rowbase * 128);
    }
    __syncthreads();                          // drain DMA -> tile resident

#pragma unroll
    for (int kk = 0; kk < 4; ++kk) {
      bf16x8 af[2], bfr[4];
      uint4 qv;
#pragma unroll
      for (int m = 0; m < 2; ++m) {
        const int row = wr * 32 + m * 16 + fr;
        const int s0  = kk * 8 + g * 2;       // 16-B slot of this lane's k8 (f32)
        f32x4 a0 = *(const f32x4*)&As[row * 128 + (((s0    ) ^ (row & 15)) * 4)];
        f32x4 a1 = *(const f32x4*)&As[row * 128 + (((s0 + 1) ^ (row & 15)) * 4)];
        unsigned int* ap = (unsigned int*)&af[m];
        ap[0] = pk2(a0.x, a0.y); ap[1] = pk2(a0.z, a0.w);
        ap[2] = pk2(a1.x, a1.y); ap[3] = pk2(a1.z, a1.w);
        if (wc == 0) {
          if (m == 0) { qv.x = quant4(a0); qv.y = quant4(a1); }
          else        { qv.z = quant4(a0); qv.w = quant4(a1); }
        }
      }
      if (wc == 0) {
        const int G = z * 64 + t * 4 + kk;    // absolute 32-col K-group
        *(uint4*)(adj8 + tbase + (size_t)(G * 2 + wr) * 1024 + (size_t)lane * 16) = qv;
      }
#pragma unroll
      for (int n = 0; n < 4; ++n) {
        const int e = wc * 64 + n * 16 + fr;
        bfr[n] = *(const bf16x8*)&Bs[e * 128 + (((kk * 4 + g) ^ (e & 15)) * 8)];
      }
#pragma unroll
      for (int m = 0; m < 2; ++m)
#pragma unroll
        for (int n = 0; n < 4; ++n)
          acc[m][n] = __builtin_amdgcn_mfma_f32_16x16x32_bf16(af[m], bfr[n], acc[m][n], 0, 0, 0);
    }
    __syncthreads();                          // protect LDS overwrite next step
  }

  // epilogue: mean over (r,z) via atomics; acc already IS tmp-partial (cols = e)
  float* gOA = outacc1 + (size_t)row0 * D_;
#pragma unroll
  for (int m = 0; m < 2; ++m)
#pragma unroll
    for (int n = 0; n < 4; ++n)
#pragma unroll
      for (int j = 0; j < 4; ++j) {
        int rl = wr * 32 + m * 16 + cr4 + j;
        int cl = wc * 64 + n * 16 + fr;
        atomicAdd(&gOA[(size_t)rl * D_ + cl], acc[m][n][j] * 0.125f);
      }
}

// ---- Layer-2 GEMM (R14 main loop): u8 tiled adj, BK=64, mf1/nf8 waves;
//      B from ET2[r] (relu+1/256 pre-folded); epilogue atomics into outacc2. ----
__global__ __launch_bounds__(256, 4) void gcn_gemm2(
    const unsigned char* __restrict__ adj8,   // tiled u8 (from gemm1)
    const unsigned short* __restrict__ ET2,   // [R][D][N] bf16
    float* __restrict__ outacc2)              // [N][D] f32 atomic accumulator
{
  __shared__ unsigned char  A8[64 * 64];      // 4 KB: linear copy of one step-tile
  __shared__ unsigned short Bs[D_ * 64];      // 16 KB: slot s stored at s^(e&7)

  const int tid  = threadIdx.x;
  const int lane = tid & 63;
  const int w    = tid >> 6;                  // wave w: rows w*16 .. w*16+16
  const int fr   = lane & 15;
  const int g    = lane >> 4;
  const int cr4  = g * 4;

  const int ntile = blockIdx.x;
  const int r     = blockIdx.y;
  const int z     = blockIdx.z;
  const int row0  = ntile * BM;
  const int k0    = z * (N_ / KSPLIT);
  const size_t tbase = (size_t)(r * 64 + ntile) * 262144;
  const unsigned short* Er = ET2 + (size_t)r * D_ * N_;

  f32x4 acc[8];
#pragma unroll
  for (int n = 0; n < 8; ++n)
    acc[n] = (f32x4){0.f, 0.f, 0.f, 0.f};

  for (int t = 0; t < 32; ++t) {              // BK=64 steps
    const int S = z * 32 + t;
    gld16(adj8 + tbase + (size_t)S * 4096 + (size_t)w * 1024 + (size_t)lane * 16,
          A8 + w * 1024);
#pragma unroll
    for (int i = 0; i < 4; ++i) {
      const int rowbase = (w * 4 + i) * 8;
      const int e    = rowbase + (lane >> 3);
      const int slot = (lane & 7) ^ (e & 7);
      gld16(Er + (size_t)e * N_ + k0 + t * 64 + slot * 8, Bs + rowbase * 64);
    }
    __syncthreads();

#pragma unroll
    for (int kk = 0; kk < 2; ++kk) {
      unsigned long long v = *(const unsigned long long*)
          &A8[((kk * 2 + (w >> 1)) * 64 + lane) * 16 + (w & 1) * 8];
      bf16x8 af;
      unsigned int* ap = (unsigned int*)&af;
      ap[0] = pk2((float)((unsigned)(v      ) & 255), (float)((unsigned)(v >>  8) & 255));
      ap[1] = pk2((float)((unsigned)(v >> 16) & 255), (float)((unsigned)(v >> 24) & 255));
      ap[2] = pk2((float)((unsigned)(v >> 32) & 255), (float)((unsigned)(v >> 40) & 255));
      ap[3] = pk2((float)((unsigned)(v >> 48) & 255), (float)((unsigned)(v >> 56) & 255));
#pragma unroll
      for (int n = 0; n < 8; ++n) {
        const int e = n * 16 + fr;
        bf16x8 bfr = *(const bf16x8*)&Bs[e * 64 + (((kk * 4 + g) ^ (e & 7)) * 8)];
        acc[n] = __builtin_amdgcn_mfma_f32_16x16x32_bf16(af, bfr, acc[n], 0, 0, 0);
      }
    }
    __syncthreads();
  }

#pragma unroll
  for (int n = 0; n < 8; ++n)
#pragma unroll
    for (int j = 0; j < 4; ++j) {
      int rl = w * 16 + cr4 + j;
      int cl = n * 16 + fr;
      atomicAdd(&outacc2[(size_t)(row0 + rl) * D_ + cl], acc[n][j] * 0.125f);
    }
}

// finish: out = relu(outacc2)
__global__ void k_finish(const float* __restrict__ outacc2, float* __restrict__ out) {
  int i = blockIdx.x * 256 + threadIdx.x;
  float v = outacc2[i];
  out[i] = v > 0.f ? v : 0.f;
}

extern "C" void kernel_launch(void* const* d_in, const int* in_sizes, int n_in,
                              void* d_out, int out_size, void* d_ws, size_t ws_size,
                              hipStream_t stream) {
  const float* adj = (const float*)d_in[0];   // [R][N][N]
  const float* emb = (const float*)d_in[1];   // [N][D]
  const float* rel = (const float*)d_in[2];   // [R][D][D]
  float* out = (float*)d_out;                 // [N][D] f32

  unsigned short* embN   = (unsigned short*)d_ws;                 // 1 MB
  unsigned short* relb   = embN + (size_t)N_ * D_;                // 256 KB
  unsigned short* ET1    = relb + (size_t)R_ * D_ * D_;           // 8 MB
  unsigned short* ET2    = ET1 + (size_t)R_ * D_ * N_;            // 8 MB
  float*          outa1  = (float*)(ET2 + (size_t)R_ * D_ * N_);  // 2 MB
  float*          outa2  = outa1 + (size_t)N_ * D_;               // 2 MB
  unsigned char*  adj8   = (unsigned char*)(outa2 + (size_t)N_ * D_);  // 128 MB

  k_init<<<6656, 256, 0, stream>>>(emb, rel, embN, relb, outa1, outa2);
  dim3 eg(N_ / 64, R_);
  k_makeET1<<<eg, 256, 0, stream>>>(relb, embN, ET1);

  dim3 grid(N_ / BM, R_, KSPLIT);
  gcn_gemm1<<<grid, 256, 0, stream>>>(adj, ET1, adj8, outa1);
  k_makeET2<<<eg, 256, 0, stream>>>(relb, outa1, ET2);
  gcn_gemm2<<<grid, 256, 0, stream>>>(adj8, ET2, outa2);
  k_finish<<<(N_ * D_) / 256, 256, 0, stream>>>(outa2, out);
}

// Round 19
// 237.703 us; speedup vs baseline: 1.0768x; 1.0740x over previous
//
#include <hip/hip_runtime.h>

#define R_ 8
#define N_ 4096
#define D_ 128
#define BM 64
#define KSPLIT 2

typedef __attribute__((ext_vector_type(8))) short bf16x8;
typedef __attribute__((ext_vector_type(4))) float f32x4;

__device__ __forceinline__ unsigned short f2bf(float f) {
  unsigned int u = __builtin_bit_cast(unsigned int, f);
  u += 0x7FFFu + ((u >> 16) & 1u);   // RNE
  return (unsigned short)(u >> 16);
}
__device__ __forceinline__ unsigned int pk2(float lo, float hi) {
  return (unsigned int)f2bf(lo) | ((unsigned int)f2bf(hi) << 16);
}
// hardware packed f32x2 -> bf16x2, RNE (same rounding as pk2). Non-volatile:
// schedulable/CSE-able. Replaces ~9 VALU ops with 1 in the conversion hot paths.
__device__ __forceinline__ unsigned int pk2cvt(float lo, float hi) {
  unsigned int r;
  asm("v_cvt_pk_bf16_f32 %0, %1, %2" : "=v"(r) : "v"(lo), "v"(hi));
  return r;
}
// quantize 4 floats in [0,1) to u8 (value*256, RN, clamp 255), packed LE
__device__ __forceinline__ unsigned int quant4(f32x4 a) {
  unsigned int q0 = (unsigned int)fminf(fmaf(a.x, 256.f, 0.5f), 255.5f);
  unsigned int q1 = (unsigned int)fminf(fmaf(a.y, 256.f, 0.5f), 255.5f);
  unsigned int q2 = (unsigned int)fminf(fmaf(a.z, 256.f, 0.5f), 255.5f);
  unsigned int q3 = (unsigned int)fminf(fmaf(a.w, 256.f, 0.5f), 255.5f);
  return q0 | (q1 << 8) | (q2 << 16) | (q3 << 24);
}

// async global->LDS, 16 B per lane; LDS dest is wave-uniform base + lane*16
__device__ __forceinline__ void gld16(const void* g, void* l) {
  using GP = const __attribute__((address_space(1))) unsigned int*;
  using LP = __attribute__((address_space(3))) unsigned int*;
  __builtin_amdgcn_global_load_lds((GP)g, (LP)l, 16, 0, 0);
}

// embT[d][n] = bf16(emb[n][d])  (unscaled: layer-1 B operand)
__global__ void k_init_embT(const float* __restrict__ emb, unsigned short* __restrict__ embT) {
  int i = blockIdx.x * 256 + threadIdx.x;     // i indexes embT flat [d][n]
  int d = i >> 12, n = i & 4095;
  embT[i] = f2bf(emb[(size_t)n * D_ + d]);
}

__global__ void k_init_rel(const float* __restrict__ rel, unsigned short* __restrict__ relb) {
  int i = blockIdx.x * 256 + threadIdx.x;     // over R*D*D
  relb[i] = f2bf(rel[i]);
}

// ---- Layer-1 GEMM (R14 structure): fp32 adj, BK=128, fused u8 quant-out;
//      A-fragment conversion via hardware v_cvt_pk_bf16_f32. ----
__global__ __launch_bounds__(256, 2) void gcn_gemm1(
    const float* __restrict__ adj,            // [R][N][N] fp32
    const unsigned short* __restrict__ embT,  // [D][N] bf16 (B^T layout)
    unsigned char* __restrict__ adj8,         // [R*64 tiles][256 KB] u8 tiled
    unsigned short* __restrict__ agg_p)       // [KSPLIT][R][N][D] bf16
{
  __shared__ float          As[BM * 128];     // 32 KB: slot s stored at s^(row&15)
  __shared__ unsigned short Bs[D_ * 128];     // 32 KB: slot s stored at s^(d&15)

  const int tid  = threadIdx.x;
  const int lane = tid & 63;
  const int w    = tid >> 6;
  const int wr = w >> 1, wc = w & 1;          // 2x2 waves: 32 rows x 64 cols each
  const int fr  = lane & 15;
  const int g   = lane >> 4;                  // 0..3
  const int cr4 = g * 4;

  const int ntile = blockIdx.x;
  const int r     = blockIdx.y;
  const int z     = blockIdx.z;
  const int row0  = ntile * BM;
  const int k0    = z * (N_ / KSPLIT);
  const size_t tbase = (size_t)(r * 64 + ntile) * 262144;   // 256 KB per tile

  const float* gAr = adj + ((size_t)r * N_ + row0) * N_ + k0;

  f32x4 acc[2][4];
#pragma unroll
  for (int m = 0; m < 2; ++m)
#pragma unroll
    for (int n = 0; n < 4; ++n)
      acc[m][n] = (f32x4){0.f, 0.f, 0.f, 0.f};

  for (int t = 0; t < 16; ++t) {              // NSTEP = 2048/128
    const int ko = t * 128;
    // A: 8 instrs/wave, each 1 KB = 2 rows x 512 B (32 slots); source pre-swizzled
#pragma unroll
    for (int i = 0; i < 8; ++i) {
      const int rowbase = w * 16 + i * 2;
      const int ra   = rowbase + (lane >> 5);
      const int slot = (lane & 31) ^ (ra & 15);
      gld16(gAr + (size_t)ra * N_ + ko + slot * 4, As + rowbase * 128);
    }
    // B: 8 instrs/wave, each 1 KB = 4 rows x 256 B (16 slots); source pre-swizzled
#pragma unroll
    for (int i = 0; i < 8; ++i) {
      const int rowbase = (w * 8 + i) * 4;
      const int d    = rowbase + (lane >> 4);
      const int slot = (lane & 15) ^ (d & 15);
      gld16(embT + (size_t)d * N_ + k0 + ko + slot * 8, Bs + rowbase * 128);
    }
    __syncthreads();                          // drain DMA -> tile resident

#pragma unroll
    for (int kk = 0; kk < 4; ++kk) {
      bf16x8 af[2], bfr[4];
      uint4 qv;
#pragma unroll
      for (int m = 0; m < 2; ++m) {
        const int row = wr * 32 + m * 16 + fr;
        const int s0  = kk * 8 + g * 2;       // 16-B slot of this lane's k8 (f32)
        f32x4 a0 = *(const f32x4*)&As[row * 128 + (((s0    ) ^ (row & 15)) * 4)];
        f32x4 a1 = *(const f32x4*)&As[row * 128 + (((s0 + 1) ^ (row & 15)) * 4)];
        unsigned int* ap = (unsigned int*)&af[m];
        ap[0] = pk2cvt(a0.x, a0.y); ap[1] = pk2cvt(a0.z, a0.w);
        ap[2] = pk2cvt(a1.x, a1.y); ap[3] = pk2cvt(a1.z, a1.w);
        if (wc == 0) {
          if (m == 0) { qv.x = quant4(a0); qv.y = quant4(a1); }
          else        { qv.z = quant4(a0); qv.w = quant4(a1); }
        }
      }
      if (wc == 0) {
        const int G = z * 64 + t * 4 + kk;    // absolute 32-col K-group
        *(uint4*)(adj8 + tbase + (size_t)(G * 2 + wr) * 1024 + (size_t)lane * 16) = qv;
      }
#pragma unroll
      for (int n = 0; n < 4; ++n) {
        const int d = wc * 64 + n * 16 + fr;
        bfr[n] = *(const bf16x8*)&Bs[d * 128 + (((kk * 4 + g) ^ (d & 15)) * 8)];
      }
#pragma unroll
      for (int m = 0; m < 2; ++m)
#pragma unroll
        for (int n = 0; n < 4; ++n)
          acc[m][n] = __builtin_amdgcn_mfma_f32_16x16x32_bf16(af[m], bfr[n], acc[m][n], 0, 0, 0);
    }
    __syncthreads();                          // protect LDS overwrite next step
  }

  unsigned short* gO = agg_p + (((size_t)z * R_ + r) * N_ + row0) * D_;
#pragma unroll
  for (int m = 0; m < 2; ++m)
#pragma unroll
    for (int n = 0; n < 4; ++n)
#pragma unroll
      for (int j = 0; j < 4; ++j) {
        int rl = wr * 32 + m * 16 + cr4 + j;
        int cl = wc * 64 + n * 16 + fr;
        gO[(size_t)rl * D_ + cl] = f2bf(acc[m][n][j]);
      }
}

// ---- Layer-2 GEMM (R14 structure): u8 tiled adj, BK=64, mf1/nf8 waves;
//      dequant via cvt_f32_ubyte-style extracts + hardware cvt_pk pack. ----
__global__ __launch_bounds__(256, 4) void gcn_gemm2(
    const unsigned char* __restrict__ adj8,   // tiled u8 (from gemm1)
    const unsigned short* __restrict__ embT,  // [D][N] bf16, scaled 1/256
    unsigned short* __restrict__ agg_p)       // [KSPLIT][R][N][D] bf16
{
  __shared__ unsigned char  A8[64 * 64];      // 4 KB: linear copy of one step-tile
  __shared__ unsigned short Bs[D_ * 64];      // 16 KB: slot s stored at s^(d&7)

  const int tid  = threadIdx.x;
  const int lane = tid & 63;
  const int w    = tid >> 6;                  // wave w: rows w*16 .. w*16+16
  const int fr   = lane & 15;
  const int g    = lane >> 4;
  const int cr4  = g * 4;

  const int ntile = blockIdx.x;
  const int r     = blockIdx.y;
  const int z     = blockIdx.z;
  const int row0  = ntile * BM;
  const int k0    = z * (N_ / KSPLIT);
  const size_t tbase = (size_t)(r * 64 + ntile) * 262144;

  f32x4 acc[8];
#pragma unroll
  for (int n = 0; n < 8; ++n)
    acc[n] = (f32x4){0.f, 0.f, 0.f, 0.f};

  for (int t = 0; t < 32; ++t) {              // BK=64 steps
    const int S = z * 32 + t;
    // A: 1 instr/wave; wave w stages chunk w (1 KB), pure sequential memcpy
    gld16(adj8 + tbase + (size_t)S * 4096 + (size_t)w * 1024 + (size_t)lane * 16,
          A8 + w * 1024);
    // B: 4 instrs/wave, each 1 KB = 8 rows x 128 B (8 slots); source pre-swizzled
#pragma unroll
    for (int i = 0; i < 4; ++i) {
      const int rowbase = (w * 4 + i) * 8;
      const int rb   = rowbase + (lane >> 3);
      const int slot = (lane & 7) ^ (rb & 7);
      gld16(embT + (size_t)rb * N_ + k0 + t * 64 + slot * 8, Bs + rowbase * 64);
    }
    __syncthreads();

#pragma unroll
    for (int kk = 0; kk < 2; ++kk) {
      // A-frag: row = w*16+fr -> writer keying (wr=w>>1, m=w&1): 8B at
      // (kk*2 + (w>>1))*1024 + lane*16 + (w&1)*8
      unsigned long long v = *(const unsigned long long*)
          &A8[((kk * 2 + (w >> 1)) * 64 + lane) * 16 + (w & 1) * 8];
      const unsigned int vl = (unsigned int)v, vh = (unsigned int)(v >> 32);
      bf16x8 af;
      unsigned int* ap = (unsigned int*)&af;
      // byte extracts compile to v_cvt_f32_ubyteN; pack via hardware cvt_pk
      ap[0] = pk2cvt((float)(vl & 255), (float)((vl >> 8) & 255));
      ap[1] = pk2cvt((float)((vl >> 16) & 255), (float)(vl >> 24));
      ap[2] = pk2cvt((float)(vh & 255), (float)((vh >> 8) & 255));
      ap[3] = pk2cvt((float)((vh >> 16) & 255), (float)(vh >> 24));
#pragma unroll
      for (int n = 0; n < 8; ++n) {
        const int d = n * 16 + fr;
        bf16x8 bfr = *(const bf16x8*)&Bs[d * 64 + (((kk * 4 + g) ^ (d & 7)) * 8)];
        acc[n] = __builtin_amdgcn_mfma_f32_16x16x32_bf16(af, bfr, acc[n], 0, 0, 0);
      }
    }
    __syncthreads();
  }

  unsigned short* gO = agg_p + (((size_t)z * R_ + r) * N_ + row0) * D_;
#pragma unroll
  for (int n = 0; n < 8; ++n)
#pragma unroll
    for (int j = 0; j < 4; ++j) {
      int rl = w * 16 + cr4 + j;
      int cl = n * 16 + fr;
      gO[(size_t)rl * D_ + cl] = f2bf(acc[n][j]);
    }
}

// Pass 2: tmp = agg_p @ rel^T summed over z,r; out = relu(mean_r); embT (scaled) for layer 2
__global__ __launch_bounds__(256) void gcn_pass2(
    const unsigned short* __restrict__ agg_p,  // [KSPLIT][R][N][D] bf16
    const unsigned short* __restrict__ relb,   // [R][D][D] bf16
    float* __restrict__ out,                   // [N][D] f32
    unsigned short* __restrict__ embT,         // [D][N] bf16
    int write_out, int write_embT)
{
  const int tid  = threadIdx.x;
  const int lane = tid & 63;
  const int w    = tid >> 6;
  const int n0   = blockIdx.x * 16;
  const int col0 = w * 32;
  const int fr   = lane & 15;
  const int e8   = (lane >> 4) * 8;
  const int cr4  = (lane >> 4) * 4;

  f32x4 tacc[2];
  tacc[0] = (f32x4){0.f, 0.f, 0.f, 0.f};
  tacc[1] = (f32x4){0.f, 0.f, 0.f, 0.f};

  for (int r = 0; r < R_; ++r) {
    bf16x8 a[2][4], b[2][4];
#pragma unroll
    for (int zz = 0; zz < 2; ++zz)
#pragma unroll
      for (int kk = 0; kk < 4; ++kk)
        a[zz][kk] = *(const bf16x8*)&agg_p[(((size_t)zz * R_ + r) * N_ + n0 + fr) * D_ + kk * 32 + e8];
#pragma unroll
    for (int n = 0; n < 2; ++n)
#pragma unroll
      for (int kk = 0; kk < 4; ++kk)
        b[n][kk] = *(const bf16x8*)&relb[(size_t)r * D_ * D_ + (col0 + n * 16 + fr) * D_ + kk * 32 + e8];
#pragma unroll
    for (int n = 0; n < 2; ++n)
#pragma unroll
      for (int kk = 0; kk < 4; ++kk)
#pragma unroll
        for (int zz = 0; zz < 2; ++zz)
          tacc[n] = __builtin_amdgcn_mfma_f32_16x16x32_bf16(a[zz][kk], b[n][kk], tacc[n], 0, 0, 0);
  }

#pragma unroll
  for (int n = 0; n < 2; ++n)
#pragma unroll
    for (int j = 0; j < 4; ++j) {
      int row = n0 + cr4 + j;
      int col = col0 + n * 16 + fr;
      float v = tacc[n][j] * 0.125f;
      v = v > 0.f ? v : 0.f;
      if (write_out)  out[(size_t)row * D_ + col] = v;
      if (write_embT) embT[(size_t)col * N_ + row] = f2bf(v * 0.00390625f);  // fold 1/256 for u8 layer-2
    }
}

extern "C" void kernel_launch(void* const* d_in, const int* in_sizes, int n_in,
                              void* d_out, int out_size, void* d_ws, size_t ws_size,
                              hipStream_t stream) {
  const float* adj = (const float*)d_in[0];   // [R][N][N]
  const float* emb = (const float*)d_in[1];   // [N][D]
  const float* rel = (const float*)d_in[2];   // [R][D][D]
  float* out = (float*)d_out;                 // [N][D] f32

  unsigned short* embT  = (unsigned short*)d_ws;                 // 1 MB
  unsigned short* relb  = embT + (size_t)N_ * D_;                // 256 KB
  unsigned short* agg_p = relb + (size_t)R_ * D_ * D_;           // 16 MB
  unsigned char*  adj8  = (unsigned char*)(agg_p + (size_t)2 * R_ * N_ * D_);  // 128 MB

  k_init_embT<<<(N_ * D_) / 256, 256, 0, stream>>>(emb, embT);
  k_init_rel<<<(R_ * D_ * D_) / 256, 256, 0, stream>>>(rel, relb);

  dim3 grid(N_ / BM, R_, KSPLIT);
  gcn_gemm1<<<grid, 256, 0, stream>>>(adj, embT, adj8, agg_p);
  gcn_pass2<<<N_ / 16, 256, 0, stream>>>(agg_p, relb, out, embT, /*write_out=*/0, /*write_embT=*/1);
  gcn_gemm2<<<grid, 256, 0, stream>>>(adj8, embT, agg_p);
  gcn_pass2<<<N_ / 16, 256, 0, stream>>>(agg_p, relb, out, embT, /*write_out=*/1, /*write_embT=*/0);
}

// Round 20
// 221.402 us; speedup vs baseline: 1.1561x; 1.0736x over previous
//
#include <hip/hip_runtime.h>

#define R_ 8
#define N_ 4096
#define D_ 128
#define BM 64
#define KSPLIT 2

typedef __attribute__((ext_vector_type(8))) short bf16x8;
typedef __attribute__((ext_vector_type(4))) float f32x4;

__device__ __forceinline__ unsigned short f2bf(float f) {
  unsigned int u = __builtin_bit_cast(unsigned int, f);
  u += 0x7FFFu + ((u >> 16) & 1u);   // RNE
  return (unsigned short)(u >> 16);
}
// hardware packed f32x2 -> bf16x2 (RNE), schedulable
__device__ __forceinline__ unsigned int pk2cvt(float lo, float hi) {
  unsigned int r;
  asm("v_cvt_pk_bf16_f32 %0, %1, %2" : "=v"(r) : "v"(lo), "v"(hi));
  return r;
}
// pack 4 f32 -> 4 fp8 e4m3 (OCP) in one dword, RNE
__device__ __forceinline__ unsigned int pk4fp8(float a, float b, float c, float d) {
  int v = __builtin_amdgcn_cvt_pk_fp8_f32(a, b, 0, false);
  v = __builtin_amdgcn_cvt_pk_fp8_f32(c, d, v, true);
  return (unsigned int)v;
}

// async global->LDS, 16 B per lane; LDS dest is wave-uniform base + lane*16
__device__ __forceinline__ void gld16(const void* g, void* l) {
  using GP = const __attribute__((address_space(1))) unsigned int*;
  using LP = __attribute__((address_space(3))) unsigned int*;
  __builtin_amdgcn_global_load_lds((GP)g, (LP)l, 16, 0, 0);
}

// embT[d][n] = bf16(emb[n][d])  (unscaled: layer-1 B operand)
__global__ void k_init_embT(const float* __restrict__ emb, unsigned short* __restrict__ embT) {
  int i = blockIdx.x * 256 + threadIdx.x;     // i indexes embT flat [d][n]
  int d = i >> 12, n = i & 4095;
  embT[i] = f2bf(emb[(size_t)n * D_ + d]);
}

__global__ void k_init_rel(const float* __restrict__ rel, unsigned short* __restrict__ relb) {
  int i = blockIdx.x * 256 + threadIdx.x;     // over R*D*D
  relb[i] = f2bf(rel[i]);
}

// ---- Layer-1 GEMM (R19 structure): fp32 adj, BK=128, bf16 MFMA; fused fp8 copy.
// adjf8 layout per (r,ntile), 256 KB: K-group G = z*64+t*4+kk (32 k each);
//   chunk (G*2+wr)*1024: [m0: 64 lanes x 8 B][m1: +512] — lane-keyed fragments.
__global__ __launch_bounds__(256, 2) void gcn_gemm1(
    const float* __restrict__ adj,            // [R][N][N] fp32
    const unsigned short* __restrict__ embT,  // [D][N] bf16 (B^T layout)
    unsigned char* __restrict__ adjf8,        // [R*64 tiles][256 KB] fp8 tiled
    unsigned short* __restrict__ agg_p)       // [KSPLIT][R][N][D] bf16
{
  __shared__ float          As[BM * 128];     // 32 KB: slot s stored at s^(row&15)
  __shared__ unsigned short Bs[D_ * 128];     // 32 KB: slot s stored at s^(d&15)

  const int tid  = threadIdx.x;
  const int lane = tid & 63;
  const int w    = tid >> 6;
  const int wr = w >> 1, wc = w & 1;          // 2x2 waves: 32 rows x 64 cols each
  const int fr  = lane & 15;
  const int g   = lane >> 4;                  // 0..3
  const int cr4 = g * 4;

  const int ntile = blockIdx.x;
  const int r     = blockIdx.y;
  const int z     = blockIdx.z;
  const int row0  = ntile * BM;
  const int k0    = z * (N_ / KSPLIT);
  const size_t tbase = (size_t)(r * 64 + ntile) * 262144;   // 256 KB per tile

  const float* gAr = adj + ((size_t)r * N_ + row0) * N_ + k0;

  f32x4 acc[2][4];
#pragma unroll
  for (int m = 0; m < 2; ++m)
#pragma unroll
    for (int n = 0; n < 4; ++n)
      acc[m][n] = (f32x4){0.f, 0.f, 0.f, 0.f};

  for (int t = 0; t < 16; ++t) {              // NSTEP = 2048/128
    const int ko = t * 128;
    // A: 8 instrs/wave, each 1 KB = 2 rows x 512 B (32 slots); source pre-swizzled
#pragma unroll
    for (int i = 0; i < 8; ++i) {
      const int rowbase = w * 16 + i * 2;
      const int ra   = rowbase + (lane >> 5);
      const int slot = (lane & 31) ^ (ra & 15);
      gld16(gAr + (size_t)ra * N_ + ko + slot * 4, As + rowbase * 128);
    }
    // B: 8 instrs/wave, each 1 KB = 4 rows x 256 B (16 slots); source pre-swizzled
#pragma unroll
    for (int i = 0; i < 8; ++i) {
      const int rowbase = (w * 8 + i) * 4;
      const int d    = rowbase + (lane >> 4);
      const int slot = (lane & 15) ^ (d & 15);
      gld16(embT + (size_t)d * N_ + k0 + ko + slot * 8, Bs + rowbase * 128);
    }
    __syncthreads();                          // drain DMA -> tile resident

#pragma unroll
    for (int kk = 0; kk < 4; ++kk) {
      bf16x8 af[2], bfr[4];
      unsigned int q0 = 0, q1 = 0, q2 = 0, q3 = 0;
#pragma unroll
      for (int m = 0; m < 2; ++m) {
        const int row = wr * 32 + m * 16 + fr;
        const int s0  = kk * 8 + g * 2;       // 16-B slot of this lane's k8 (f32)
        f32x4 a0 = *(const f32x4*)&As[row * 128 + (((s0    ) ^ (row & 15)) * 4)];
        f32x4 a1 = *(const f32x4*)&As[row * 128 + (((s0 + 1) ^ (row & 15)) * 4)];
        unsigned int* ap = (unsigned int*)&af[m];
        ap[0] = pk2cvt(a0.x, a0.y); ap[1] = pk2cvt(a0.z, a0.w);
        ap[2] = pk2cvt(a1.x, a1.y); ap[3] = pk2cvt(a1.z, a1.w);
        if (wc == 0) {
          if (m == 0) { q0 = pk4fp8(a0.x, a0.y, a0.z, a0.w); q1 = pk4fp8(a1.x, a1.y, a1.z, a1.w); }
          else        { q2 = pk4fp8(a0.x, a0.y, a0.z, a0.w); q3 = pk4fp8(a1.x, a1.y, a1.z, a1.w); }
        }
      }
      if (wc == 0) {
        const int G = z * 64 + t * 4 + kk;    // absolute 32-col K-group
        unsigned char* p = adjf8 + tbase + (size_t)(G * 2 + wr) * 1024 + (size_t)lane * 8;
        *(uint2*)p         = (uint2){q0, q1};   // m0 fragment (8 fp8)
        *(uint2*)(p + 512) = (uint2){q2, q3};   // m1 fragment
      }
#pragma unroll
      for (int n = 0; n < 4; ++n) {
        const int d = wc * 64 + n * 16 + fr;
        bfr[n] = *(const bf16x8*)&Bs[d * 128 + (((kk * 4 + g) ^ (d & 15)) * 8)];
      }
#pragma unroll
      for (int m = 0; m < 2; ++m)
#pragma unroll
        for (int n = 0; n < 4; ++n)
          acc[m][n] = __builtin_amdgcn_mfma_f32_16x16x32_bf16(af[m], bfr[n], acc[m][n], 0, 0, 0);
    }
    __syncthreads();                          // protect LDS overwrite next step
  }

  unsigned short* gO = agg_p + (((size_t)z * R_ + r) * N_ + row0) * D_;
#pragma unroll
  for (int m = 0; m < 2; ++m)
#pragma unroll
    for (int n = 0; n < 4; ++n)
#pragma unroll
      for (int j = 0; j < 4; ++j) {
        int rl = wr * 32 + m * 16 + cr4 + j;
        int cl = wc * 64 + n * 16 + fr;
        gO[(size_t)rl * D_ + cl] = f2bf(acc[m][n][j]);
      }
}

// ---- Layer-2 GEMM: native fp8 MFMA, zero dequant. A from adjf8 tiled, B from
//      embT8t tiled (both sequential staging, lane-keyed conflict-free reads). ----
__global__ __launch_bounds__(256, 4) void gcn_gemm2(
    const unsigned char* __restrict__ adjf8,  // tiled fp8 (from gemm1)
    const unsigned char* __restrict__ embT8t, // tiled fp8 emb2 * 2^-16
    unsigned short* __restrict__ agg_p)       // [KSPLIT][R][N][D] bf16, scale 2^-16
{
  __shared__ unsigned char A8[4096];          // [2 G][2 wr][2 m][64 lane][8 B]
  __shared__ unsigned char B8[8192];          // [2 G][8 DB][64 lane][8 B]

  const int tid  = threadIdx.x;
  const int lane = tid & 63;
  const int w    = tid >> 6;                  // wave w: rows w*16 .. w*16+16
  const int fr   = lane & 15;
  const int cr4  = (lane >> 4) * 4;

  const int ntile = blockIdx.x;
  const int r     = blockIdx.y;
  const int z     = blockIdx.z;
  const int row0  = ntile * BM;
  const size_t tbase = (size_t)(r * 64 + ntile) * 262144;

  f32x4 acc[8];
#pragma unroll
  for (int n = 0; n < 8; ++n)
    acc[n] = (f32x4){0.f, 0.f, 0.f, 0.f};

  for (int t = 0; t < 32; ++t) {              // BK=64 steps
    const int G0 = z * 64 + t * 2;            // two 32-k groups per step
    // A: 1 gld16/wave, 4 KB total, pure sequential
    gld16(adjf8 + tbase + (size_t)G0 * 2048 + (size_t)w * 1024 + (size_t)lane * 16,
          A8 + w * 1024);
    // B: 2 gld16/wave, 8 KB total, pure sequential
#pragma unroll
    for (int i = 0; i < 2; ++i) {
      const int c = i * 4 + w;
      gld16(embT8t + (size_t)G0 * 4096 + (size_t)c * 1024 + (size_t)lane * 16,
            B8 + c * 1024);
    }
    __syncthreads();

#pragma unroll
    for (int kk = 0; kk < 2; ++kk) {
      const long av = *(const long*)&A8[(((kk * 2 + (w >> 1)) * 2 + (w & 1)) * 64 + lane) * 8];
#pragma unroll
      for (int n = 0; n < 8; ++n) {
        const long bv = *(const long*)&B8[((kk * 8 + n) * 64 + lane) * 8];
        acc[n] = __builtin_amdgcn_mfma_f32_16x16x32_fp8_fp8(av, bv, acc[n], 0, 0, 0);
      }
    }
    __syncthreads();
  }

  unsigned short* gO = agg_p + (((size_t)z * R_ + r) * N_ + row0) * D_;
#pragma unroll
  for (int n = 0; n < 8; ++n)
#pragma unroll
    for (int j = 0; j < 4; ++j) {
      int rl = w * 16 + cr4 + j;
      int cl = n * 16 + fr;
      gO[(size_t)rl * D_ + cl] = f2bf(acc[n][j]);
    }
}

// Pass 2: tmp = agg_p @ rel^T summed over z,r.
// layer-1 (write_embT): emb2 = relu(mean) -> fp8 tiled (x 2^-16) for gemm2's B.
//   chunk(G=k>>5, DB=d>>4) 512 B; lane (d&15)+((k>>3)&3)*16 holds k..k+8 at lane*8.
// layer-2 (write_out): out = relu(mean * 2^16)  [undo the fp8 range scale].
__global__ __launch_bounds__(256) void gcn_pass2(
    const unsigned short* __restrict__ agg_p,  // [KSPLIT][R][N][D] bf16
    const unsigned short* __restrict__ relb,   // [R][D][D] bf16
    float* __restrict__ out,                   // [N][D] f32
    unsigned char* __restrict__ embT8t,        // tiled fp8
    int write_out, int write_embT)
{
  const int tid  = threadIdx.x;
  const int lane = tid & 63;
  const int w    = tid >> 6;
  const int n0   = blockIdx.x * 16;
  const int col0 = w * 32;
  const int fr   = lane & 15;
  const int e8   = (lane >> 4) * 8;
  const int cr4  = (lane >> 4) * 4;

  f32x4 tacc[2];
  tacc[0] = (f32x4){0.f, 0.f, 0.f, 0.f};
  tacc[1] = (f32x4){0.f, 0.f, 0.f, 0.f};

  for (int r = 0; r < R_; ++r) {
    bf16x8 a[2][4], b[2][4];
#pragma unroll
    for (int zz = 0; zz < 2; ++zz)
#pragma unroll
      for (int kk = 0; kk < 4; ++kk)
        a[zz][kk] = *(const bf16x8*)&agg_p[(((size_t)zz * R_ + r) * N_ + n0 + fr) * D_ + kk * 32 + e8];
#pragma unroll
    for (int n = 0; n < 2; ++n)
#pragma unroll
      for (int kk = 0; kk < 4; ++kk)
        b[n][kk] = *(const bf16x8*)&relb[(size_t)r * D_ * D_ + (col0 + n * 16 + fr) * D_ + kk * 32 + e8];
#pragma unroll
    for (int n = 0; n < 2; ++n)
#pragma unroll
      for (int kk = 0; kk < 4; ++kk)
#pragma unroll
        for (int zz = 0; zz < 2; ++zz)
          tacc[n] = __builtin_amdgcn_mfma_f32_16x16x32_bf16(a[zz][kk], b[n][kk], tacc[n], 0, 0, 0);
  }

#pragma unroll
  for (int n = 0; n < 2; ++n) {
    if (write_out) {
#pragma unroll
      for (int j = 0; j < 4; ++j) {
        int row = n0 + cr4 + j;
        int col = col0 + n * 16 + fr;
        float v = tacc[n][j] * 8192.f;        // 0.125 mean * 2^16 fp8-scale undo
        out[(size_t)row * D_ + col] = v > 0.f ? v : 0.f;
      }
    }
    if (write_embT) {
      const float s = 0.125f * 1.52587890625e-05f;   // mean * 2^-16 range scale
      float v[4];
#pragma unroll
      for (int j = 0; j < 4; ++j) {
        float x = tacc[n][j];
        v[j] = (x > 0.f ? x : 0.f) * s;
      }
      unsigned int pk = pk4fp8(v[0], v[1], v[2], v[3]);
      const int G   = n0 >> 5;
      const int gfr = ((n0 & 31) + cr4) >> 3;
      const int h   = (cr4 >> 2) & 1;
      const int DB  = w * 2 + n;
      *(unsigned int*)(embT8t + (size_t)(G * 8 + DB) * 512 + (fr + gfr * 16) * 8 + h * 4) = pk;
    }
  }
}

extern "C" void kernel_launch(void* const* d_in, const int* in_sizes, int n_in,
                              void* d_out, int out_size, void* d_ws, size_t ws_size,
                              hipStream_t stream) {
  const float* adj = (const float*)d_in[0];   // [R][N][N]
  const float* emb = (const float*)d_in[1];   // [N][D]
  const float* rel = (const float*)d_in[2];   // [R][D][D]
  float* out = (float*)d_out;                 // [N][D] f32

  unsigned short* embT   = (unsigned short*)d_ws;                // 1 MB
  unsigned short* relb   = embT + (size_t)N_ * D_;               // 256 KB
  unsigned short* agg_p  = relb + (size_t)R_ * D_ * D_;          // 16 MB
  unsigned char*  embT8t = (unsigned char*)(agg_p + (size_t)2 * R_ * N_ * D_);  // 512 KB
  unsigned char*  adjf8  = embT8t + (size_t)512 * 1024;          // 128 MB

  k_init_embT<<<(N_ * D_) / 256, 256, 0, stream>>>(emb, embT);
  k_init_rel<<<(R_ * D_ * D_) / 256, 256, 0, stream>>>(rel, relb);

  dim3 grid(N_ / BM, R_, KSPLIT);
  gcn_gemm1<<<grid, 256, 0, stream>>>(adj, embT, adjf8, agg_p);
  gcn_pass2<<<N_ / 16, 256, 0, stream>>>(agg_p, relb, out, embT8t, /*write_out=*/0, /*write_embT=*/1);
  gcn_gemm2<<<grid, 256, 0, stream>>>(adjf8, embT8t, agg_p);
  gcn_pass2<<<N_ / 16, 256, 0, stream>>>(agg_p, relb, out, embT8t, /*write_out=*/1, /*write_embT=*/0);
}

// Round 21
// 216.932 us; speedup vs baseline: 1.1799x; 1.0206x over previous
//
#include <hip/hip_runtime.h>

#define R_ 8
#define N_ 4096
#define D_ 128
#define BM 64
#define KSPLIT 2

typedef __attribute__((ext_vector_type(8))) short bf16x8;
typedef __attribute__((ext_vector_type(4))) float f32x4;

__device__ __forceinline__ unsigned short f2bf(float f) {
  unsigned int u = __builtin_bit_cast(unsigned int, f);
  u += 0x7FFFu + ((u >> 16) & 1u);   // RNE
  return (unsigned short)(u >> 16);
}
// pack 4 f32 -> 4 fp8 e4m3 (OCP) in one dword, RNE
__device__ __forceinline__ unsigned int pk4fp8(float a, float b, float c, float d) {
  int v = __builtin_amdgcn_cvt_pk_fp8_f32(a, b, 0, false);
  v = __builtin_amdgcn_cvt_pk_fp8_f32(c, d, v, true);
  return (unsigned int)v;
}

// async global->LDS, 16 B per lane; LDS dest is wave-uniform base + lane*16
__device__ __forceinline__ void gld16(const void* g, void* l) {
  using GP = const __attribute__((address_space(1))) unsigned int*;
  using LP = __attribute__((address_space(3))) unsigned int*;
  __builtin_amdgcn_global_load_lds((GP)g, (LP)l, 16, 0, 0);
}

// Merged init.
// Blocks [0,256): embT8a — fp8 emb tiled in MFMA-fragment order for layer-1 B.
//   Chunk C = G*8 + DB (G = k>>5, DB = d>>4), 512 B; unit l = (d&15)+((k>>3)&3)*16
//   holds fp8 emb[k..k+8][d] at byte l*8.
// Blocks [256,768): relb = bf16(rel), layout preserved.
__global__ void k_init(const float* __restrict__ emb, const float* __restrict__ rel,
                       unsigned char* __restrict__ embT8a, unsigned short* __restrict__ relb) {
  int b = blockIdx.x;
  if (b < 256) {
    int gt = b * 256 + threadIdx.x;           // 64K units of 8 B
    int C = gt >> 6, l = gt & 63;
    int d = (C & 7) * 16 + (l & 15);
    int k = (C >> 3) * 32 + (l >> 4) * 8;
    float v[8];
#pragma unroll
    for (int i = 0; i < 8; ++i)
      v[i] = emb[(size_t)(k + i) * D_ + d];
    uint2 pk;
    pk.x = pk4fp8(v[0], v[1], v[2], v[3]);
    pk.y = pk4fp8(v[4], v[5], v[6], v[7]);
    *(uint2*)(embT8a + ((size_t)C * 64 + l) * 8) = pk;
  } else {
    int i = (b - 256) * 256 + threadIdx.x;    // over R*D*D
    relb[i] = f2bf(rel[i]);
  }
}

// ---- Layer-1 GEMM: fp32 adj staged to LDS, packed ONCE to fp8 (feeds MFMA and
//      the adjf8 copy), fp8 B from tiled embT8a. BK=128, 48 KB LDS -> 3 blocks/CU.
// adjf8 layout per (r,ntile), 256 KB: K-group G = z*64+t*4+kk; chunk (G*2+wr)*1024:
//   [m0: 64 lanes x 8 B][m1: +512] — lane-keyed fragments (reader: gcn_gemm2).
__global__ __launch_bounds__(256, 3) void gcn_gemm1(
    const float* __restrict__ adj,            // [R][N][N] fp32
    const unsigned char* __restrict__ embT8a, // tiled fp8 emb (layer-1 B)
    unsigned char* __restrict__ adjf8,        // [R*64 tiles][256 KB] fp8 tiled
    unsigned short* __restrict__ agg_p)       // [KSPLIT][R][N][D] bf16
{
  __shared__ float         As[BM * 128];      // 32 KB: slot s stored at s^(row&15)
  __shared__ unsigned char B8[16384];         // 16 KB: [4 G][8 DB][64 lane][8 B]

  const int tid  = threadIdx.x;
  const int lane = tid & 63;
  const int w    = tid >> 6;
  const int wr = w >> 1, wc = w & 1;          // 2x2 waves: 32 rows x 64 cols each
  const int fr  = lane & 15;
  const int g   = lane >> 4;                  // 0..3
  const int cr4 = g * 4;

  const int ntile = blockIdx.x;
  const int r     = blockIdx.y;
  const int z     = blockIdx.z;
  const int row0  = ntile * BM;
  const int k0    = z * (N_ / KSPLIT);
  const size_t tbase = (size_t)(r * 64 + ntile) * 262144;   // 256 KB per tile

  const float* gAr = adj + ((size_t)r * N_ + row0) * N_ + k0;

  f32x4 acc[2][4];
#pragma unroll
  for (int m = 0; m < 2; ++m)
#pragma unroll
    for (int n = 0; n < 4; ++n)
      acc[m][n] = (f32x4){0.f, 0.f, 0.f, 0.f};

  for (int t = 0; t < 16; ++t) {              // NSTEP = 2048/128
    const int ko = t * 128;
    // A: 8 instrs/wave, each 1 KB = 2 rows x 512 B (32 slots); source pre-swizzled
#pragma unroll
    for (int i = 0; i < 8; ++i) {
      const int rowbase = w * 16 + i * 2;
      const int ra   = rowbase + (lane >> 5);
      const int slot = (lane & 31) ^ (ra & 15);
      gld16(gAr + (size_t)ra * N_ + ko + slot * 4, As + rowbase * 128);
    }
    // B: 4 instrs/wave, 16 KB total, pure sequential from tiled embT8a
    {
      const unsigned char* src = embT8a + (size_t)(z * 64 + t * 4) * 4096;
#pragma unroll
      for (int i = 0; i < 4; ++i) {
        const int c = i * 4 + w;
        gld16(src + (size_t)c * 1024 + (size_t)lane * 16, B8 + c * 1024);
      }
    }
    __syncthreads();                          // drain DMA -> tile resident

#pragma unroll
    for (int kk = 0; kk < 4; ++kk) {
      unsigned long long av[2];
#pragma unroll
      for (int m = 0; m < 2; ++m) {
        const int row = wr * 32 + m * 16 + fr;
        const int s0  = kk * 8 + g * 2;       // 16-B slot of this lane's k8 (f32)
        f32x4 a0 = *(const f32x4*)&As[row * 128 + (((s0    ) ^ (row & 15)) * 4)];
        f32x4 a1 = *(const f32x4*)&As[row * 128 + (((s0 + 1) ^ (row & 15)) * 4)];
        unsigned int lo = pk4fp8(a0.x, a0.y, a0.z, a0.w);
        unsigned int hi = pk4fp8(a1.x, a1.y, a1.z, a1.w);
        av[m] = (unsigned long long)lo | ((unsigned long long)hi << 32);
      }
      if (wc == 0) {
        const int G = z * 64 + t * 4 + kk;    // absolute 32-col K-group
        unsigned char* p = adjf8 + tbase + (size_t)(G * 2 + wr) * 1024 + (size_t)lane * 8;
        *(unsigned long long*)p         = av[0];   // m0 fragment (8 fp8)
        *(unsigned long long*)(p + 512) = av[1];   // m1 fragment
      }
#pragma unroll
      for (int n = 0; n < 4; ++n) {
        const int DB = wc * 4 + n;
        const long bv = *(const long*)&B8[((kk * 8 + DB) * 64 + lane) * 8];
#pragma unroll
        for (int m = 0; m < 2; ++m)
          acc[m][n] = __builtin_amdgcn_mfma_f32_16x16x32_fp8_fp8((long)av[m], bv, acc[m][n], 0, 0, 0);
      }
    }
    __syncthreads();                          // protect LDS overwrite next step
  }

  unsigned short* gO = agg_p + (((size_t)z * R_ + r) * N_ + row0) * D_;
#pragma unroll
  for (int m = 0; m < 2; ++m)
#pragma unroll
    for (int n = 0; n < 4; ++n)
#pragma unroll
      for (int j = 0; j < 4; ++j) {
        int rl = wr * 32 + m * 16 + cr4 + j;
        int cl = wc * 64 + n * 16 + fr;
        gO[(size_t)rl * D_ + cl] = f2bf(acc[m][n][j]);
      }
}

// ---- Layer-2 GEMM (R20 verbatim): native fp8 MFMA, zero dequant ----
__global__ __launch_bounds__(256, 4) void gcn_gemm2(
    const unsigned char* __restrict__ adjf8,  // tiled fp8 (from gemm1)
    const unsigned char* __restrict__ embT8t, // tiled fp8 emb2 * 2^-16
    unsigned short* __restrict__ agg_p)       // [KSPLIT][R][N][D] bf16, scale 2^-16
{
  __shared__ unsigned char A8[4096];          // [2 G][2 wr][2 m][64 lane][8 B]
  __shared__ unsigned char B8[8192];          // [2 G][8 DB][64 lane][8 B]

  const int tid  = threadIdx.x;
  const int lane = tid & 63;
  const int w    = tid >> 6;                  // wave w: rows w*16 .. w*16+16
  const int fr   = lane & 15;
  const int cr4  = (lane >> 4) * 4;

  const int ntile = blockIdx.x;
  const int r     = blockIdx.y;
  const int z     = blockIdx.z;
  const int row0  = ntile * BM;
  const size_t tbase = (size_t)(r * 64 + ntile) * 262144;

  f32x4 acc[8];
#pragma unroll
  for (int n = 0; n < 8; ++n)
    acc[n] = (f32x4){0.f, 0.f, 0.f, 0.f};

  for (int t = 0; t < 32; ++t) {              // BK=64 steps
    const int G0 = z * 64 + t * 2;            // two 32-k groups per step
    gld16(adjf8 + tbase + (size_t)G0 * 2048 + (size_t)w * 1024 + (size_t)lane * 16,
          A8 + w * 1024);
#pragma unroll
    for (int i = 0; i < 2; ++i) {
      const int c = i * 4 + w;
      gld16(embT8t + (size_t)G0 * 4096 + (size_t)c * 1024 + (size_t)lane * 16,
            B8 + c * 1024);
    }
    __syncthreads();

#pragma unroll
    for (int kk = 0; kk < 2; ++kk) {
      const long av = *(const long*)&A8[(((kk * 2 + (w >> 1)) * 2 + (w & 1)) * 64 + lane) * 8];
#pragma unroll
      for (int n = 0; n < 8; ++n) {
        const long bv = *(const long*)&B8[((kk * 8 + n) * 64 + lane) * 8];
        acc[n] = __builtin_amdgcn_mfma_f32_16x16x32_fp8_fp8(av, bv, acc[n], 0, 0, 0);
      }
    }
    __syncthreads();
  }

  unsigned short* gO = agg_p + (((size_t)z * R_ + r) * N_ + row0) * D_;
#pragma unroll
  for (int n = 0; n < 8; ++n)
#pragma unroll
    for (int j = 0; j < 4; ++j) {
      int rl = w * 16 + cr4 + j;
      int cl = n * 16 + fr;
      gO[(size_t)rl * D_ + cl] = f2bf(acc[n][j]);
    }
}

// Pass 2 (R20 verbatim): tmp = agg_p @ rel^T summed over z,r.
__global__ __launch_bounds__(256) void gcn_pass2(
    const unsigned short* __restrict__ agg_p,  // [KSPLIT][R][N][D] bf16
    const unsigned short* __restrict__ relb,   // [R][D][D] bf16
    float* __restrict__ out,                   // [N][D] f32
    unsigned char* __restrict__ embT8t,        // tiled fp8 (layer-2 B)
    int write_out, int write_embT)
{
  const int tid  = threadIdx.x;
  const int lane = tid & 63;
  const int w    = tid >> 6;
  const int n0   = blockIdx.x * 16;
  const int col0 = w * 32;
  const int fr   = lane & 15;
  const int e8   = (lane >> 4) * 8;
  const int cr4  = (lane >> 4) * 4;

  f32x4 tacc[2];
  tacc[0] = (f32x4){0.f, 0.f, 0.f, 0.f};
  tacc[1] = (f32x4){0.f, 0.f, 0.f, 0.f};

  for (int r = 0; r < R_; ++r) {
    bf16x8 a[2][4], b[2][4];
#pragma unroll
    for (int zz = 0; zz < 2; ++zz)
#pragma unroll
      for (int kk = 0; kk < 4; ++kk)
        a[zz][kk] = *(const bf16x8*)&agg_p[(((size_t)zz * R_ + r) * N_ + n0 + fr) * D_ + kk * 32 + e8];
#pragma unroll
    for (int n = 0; n < 2; ++n)
#pragma unroll
      for (int kk = 0; kk < 4; ++kk)
        b[n][kk] = *(const bf16x8*)&relb[(size_t)r * D_ * D_ + (col0 + n * 16 + fr) * D_ + kk * 32 + e8];
#pragma unroll
    for (int n = 0; n < 2; ++n)
#pragma unroll
      for (int kk = 0; kk < 4; ++kk)
#pragma unroll
        for (int zz = 0; zz < 2; ++zz)
          tacc[n] = __builtin_amdgcn_mfma_f32_16x16x32_bf16(a[zz][kk], b[n][kk], tacc[n], 0, 0, 0);
  }

#pragma unroll
  for (int n = 0; n < 2; ++n) {
    if (write_out) {
#pragma unroll
      for (int j = 0; j < 4; ++j) {
        int row = n0 + cr4 + j;
        int col = col0 + n * 16 + fr;
        float v = tacc[n][j] * 8192.f;        // 0.125 mean * 2^16 fp8-scale undo
        out[(size_t)row * D_ + col] = v > 0.f ? v : 0.f;
      }
    }
    if (write_embT) {
      const float s = 0.125f * 1.52587890625e-05f;   // mean * 2^-16 range scale
      float v[4];
#pragma unroll
      for (int j = 0; j < 4; ++j) {
        float x = tacc[n][j];
        v[j] = (x > 0.f ? x : 0.f) * s;
      }
      unsigned int pk = pk4fp8(v[0], v[1], v[2], v[3]);
      const int G   = n0 >> 5;
      const int gfr = ((n0 & 31) + cr4) >> 3;
      const int h   = (cr4 >> 2) & 1;
      const int DB  = w * 2 + n;
      *(unsigned int*)(embT8t + (size_t)(G * 8 + DB) * 512 + (fr + gfr * 16) * 8 + h * 4) = pk;
    }
  }
}

extern "C" void kernel_launch(void* const* d_in, const int* in_sizes, int n_in,
                              void* d_out, int out_size, void* d_ws, size_t ws_size,
                              hipStream_t stream) {
  const float* adj = (const float*)d_in[0];   // [R][N][N]
  const float* emb = (const float*)d_in[1];   // [N][D]
  const float* rel = (const float*)d_in[2];   // [R][D][D]
  float* out = (float*)d_out;                 // [N][D] f32

  unsigned short* relb   = (unsigned short*)d_ws;                // 256 KB
  unsigned short* agg_p  = relb + (size_t)R_ * D_ * D_;          // 16 MB
  unsigned char*  embT8a = (unsigned char*)(agg_p + (size_t)2 * R_ * N_ * D_);  // 512 KB (L1 B)
  unsigned char*  embT8t = embT8a + (size_t)512 * 1024;          // 512 KB (L2 B)
  unsigned char*  adjf8  = embT8t + (size_t)512 * 1024;          // 128 MB

  k_init<<<768, 256, 0, stream>>>(emb, rel, embT8a, relb);

  dim3 grid(N_ / BM, R_, KSPLIT);
  gcn_gemm1<<<grid, 256, 0, stream>>>(adj, embT8a, adjf8, agg_p);
  gcn_pass2<<<N_ / 16, 256, 0, stream>>>(agg_p, relb, out, embT8t, /*write_out=*/0, /*write_embT=*/1);
  gcn_gemm2<<<grid, 256, 0, stream>>>(adjf8, embT8t, agg_p);
  gcn_pass2<<<N_ / 16, 256, 0, stream>>>(agg_p, relb, out, embT8t, /*write_out=*/1, /*write_embT=*/0);
}